// Round 8
// baseline (515.693 us; speedup 1.0000x reference)
//
#include <hip/hip_runtime.h>
#include <cstdint>
#include <math.h>

#define S_LEN 2048
#define BATCH 2
#define HID   2048
#define NHEAD 16
#define DHEAD 128

typedef _Float16 h8 __attribute__((ext_vector_type(8)));
typedef _Float16 h4 __attribute__((ext_vector_type(4)));
typedef float f32x4 __attribute__((ext_vector_type(4)));

// async global->LDS, 16B per lane; LDS dest = wave-uniform base + lane*16
__device__ __forceinline__ void gload16(const void* g, void* l) {
  __builtin_amdgcn_global_load_lds(
      (const __attribute__((address_space(1))) unsigned int*)g,
      (__attribute__((address_space(3))) unsigned int*)l, 16, 0, 0);
}

// ---------------------------------------------------------------------------
// fp16 MFMA GEMM (unchanged since R4): C[M,N] = A[M,K] @ Bt[N,K]^T (+bias).
// ~690 TF measured at K=2048 (m97-structure plateau).
// ---------------------------------------------------------------------------
template <bool HAS_BIAS, bool OUT_HALF>
__global__ __launch_bounds__(256) void gemm_mfma(
    const _Float16* __restrict__ A, const _Float16* __restrict__ Bt,
    const float* __restrict__ bias, void* __restrict__ Cout, int M, int N,
    int K) {
  __shared__ _Float16 As[128 * 32];
  __shared__ _Float16 Bs[128 * 32];
  const int tid = threadIdx.x;
  const int wave = tid >> 6, lane = tid & 63;
  const int ln = lane & 15, quad = lane >> 4;
  const int wm = wave & 1, wn = wave >> 1;
  const int bm = blockIdx.y * 128, bn = blockIdx.x * 128;

  const int sr = lane >> 2;
  const int sk = (lane & 3) * 8;
  const _Float16* ga0 = A + (size_t)(bm + 32 * wave + sr) * K + sk;
  const _Float16* ga1 = A + (size_t)(bm + 32 * wave + 16 + sr) * K + sk;
  const _Float16* gb0 = Bt + (size_t)(bn + 32 * wave + sr) * K + sk;
  const _Float16* gb1 = Bt + (size_t)(bn + 32 * wave + 16 + sr) * K + sk;
  _Float16* la0 = As + 1024 * wave;
  _Float16* la1 = As + 1024 * wave + 512;
  _Float16* lb0 = Bs + 1024 * wave;
  _Float16* lb1 = Bs + 1024 * wave + 512;

  f32x4 acc[4][4];
#pragma unroll
  for (int i = 0; i < 4; i++)
#pragma unroll
    for (int j = 0; j < 4; j++) acc[i][j] = (f32x4){0.f, 0.f, 0.f, 0.f};

  for (int kt = 0; kt < K; kt += 32) {
    __syncthreads();
    gload16(ga0 + kt, la0);
    gload16(ga1 + kt, la1);
    gload16(gb0 + kt, lb0);
    gload16(gb1 + kt, lb1);
    __syncthreads();

    h8 af[4], bf[4];
#pragma unroll
    for (int mt = 0; mt < 4; mt++)
      af[mt] = *(const h8*)&As[(wm * 64 + mt * 16 + ln) * 32 + quad * 8];
#pragma unroll
    for (int nt = 0; nt < 4; nt++)
      bf[nt] = *(const h8*)&Bs[(wn * 64 + nt * 16 + ln) * 32 + quad * 8];
#pragma unroll
    for (int mt = 0; mt < 4; mt++)
#pragma unroll
      for (int nt = 0; nt < 4; nt++)
        acc[mt][nt] = __builtin_amdgcn_mfma_f32_16x16x32_f16(
            af[mt], bf[nt], acc[mt][nt], 0, 0, 0);
  }

#pragma unroll
  for (int mt = 0; mt < 4; mt++) {
#pragma unroll
    for (int r = 0; r < 4; r++) {
      const size_t row = (size_t)(bm + wm * 64 + mt * 16 + quad * 4 + r);
#pragma unroll
      for (int nt = 0; nt < 4; nt++) {
        const int col = bn + wn * 64 + nt * 16 + ln;
        float v = acc[mt][nt][r];
        if (HAS_BIAS) v += bias[col];
        if (OUT_HALF)
          ((_Float16*)Cout)[row * N + col] = (_Float16)v;
        else
          ((float*)Cout)[row * N + col] = v;
      }
    }
  }
}

__global__ __launch_bounds__(256) void transpose_cvt(
    const float* __restrict__ in, _Float16* __restrict__ out, int K, int N) {
  __shared__ float t[64][65];
  const int bn = blockIdx.x * 64, bk = blockIdx.y * 64;
  const int l = threadIdx.x & 63, g = threadIdx.x >> 6;
#pragma unroll
  for (int i = 0; i < 16; i++) {
    int r = g + 4 * i;
    t[r][l] = in[(size_t)(bk + r) * N + bn + l];
  }
  __syncthreads();
#pragma unroll
  for (int i = 0; i < 16; i++) {
    int r = g + 4 * i;
    out[(size_t)(bn + r) * K + bk + l] = (_Float16)t[l][r];
  }
}

__global__ __launch_bounds__(256) void cvt_fp16(const float* __restrict__ in,
                                                _Float16* __restrict__ out,
                                                int n4) {
  int i = blockIdx.x * blockDim.x + threadIdx.x;
  if (i < n4) {
    float4 v = ((const float4*)in)[i];
    h4 o = {(_Float16)v.x, (_Float16)v.y, (_Float16)v.z, (_Float16)v.w};
    *(h4*)&out[4 * (size_t)i] = o;
  }
}

// ---------------------------------------------------------------------------
// pack_kv: re-lay K and V of one (z, kt) 32-row tile into MFMA-fragment lane
// order, so flash waves can read B-fragments as fully-coalesced global b128.
//   KP[((z*64+kt)*8 + jn*4+kq)*512 + lane*8 + j]
//       = K[kb+16*jn+(lane&15)][32*kq+8*(lane>>4)+j]
//   VP[((z*64+kt)*8 + nt)*512 + lane*8 + j]
//       = V[kb+8*(lane>>4)+j][16*nt+(lane&15)]
// Grid (64 kt, 32 z), 256 thr. V goes through an LDS transpose tile.
// ---------------------------------------------------------------------------
__global__ __launch_bounds__(256) void pack_kv(
    const _Float16* __restrict__ mixed, _Float16* __restrict__ KP,
    _Float16* __restrict__ VP) {
  __shared__ _Float16 Tv[128 * 40];  // [d][s], stride 40 halves (80B, 16B mult)
  const int kt = blockIdx.x;
  const int z = blockIdx.y;  // b*NH + h
  const int kb = kt * 32;
  const int tid = threadIdx.x;
  const size_t RS = (size_t)BATCH * NHEAD * 384;  // 12288 halves per seq row
  const _Float16* base = mixed + (size_t)z * 384;

  // Phase A: stage V tile transposed into Tv
  {
    const int r = tid >> 3, d0 = (tid & 7) * 16;
    const _Float16* src = base + (size_t)(kb + r) * RS + 256 + d0;
    h8 v0 = *(const h8*)src;
    h8 v1 = *(const h8*)(src + 8);
#pragma unroll
    for (int e = 0; e < 8; e++) Tv[(d0 + e) * 40 + r] = v0[e];
#pragma unroll
    for (int e = 0; e < 8; e++) Tv[(d0 + 8 + e) * 40 + r] = v1[e];
  }
  __syncthreads();

  const size_t tb = ((size_t)z * 64 + kt) * 8 * 512;
#pragma unroll
  for (int c = 0; c < 2; c++) {
    const int idx = tid + 256 * c;  // 0..511
    const int i = idx >> 6, l = idx & 63;
    const int ln = l & 15, quad = l >> 4;
    // K chunk: direct contiguous read from mixed
    {
      const int jn = i >> 2, kq = i & 3;
      h8 v = *(const h8*)(base + (size_t)(kb + 16 * jn + ln) * RS + 128 +
                          32 * kq + 8 * quad);
      *(h8*)&KP[tb + (size_t)i * 512 + l * 8] = v;
    }
    // V chunk: from transposed LDS tile
    {
      h8 v = *(const h8*)&Tv[(16 * i + ln) * 40 + 8 * quad];
      *(h8*)&VP[tb + (size_t)i * 512 + l * 8] = v;
    }
  }
}

// ---------------------------------------------------------------------------
// fp16-MFMA flash attention v6: ZERO barriers, ZERO K/V staging.
// Grid (S/64, NH, B), 256 thr (4 independent waves; wave owns 16 q-rows).
// K/V fragments read directly global->VGPR from pre-packed KP/VP (fully
// coalesced: addr = tile_base + i*512 + lane*8 halves). LDS = St only
// (wave-private P round-trip, no cross-wave deps -> no __syncthreads).
// No-max softmax (R5-proven). Q frags in registers, pre-scaled.
// ---------------------------------------------------------------------------
__global__ __launch_bounds__(256, 4) void flash_attn_v6(
    const _Float16* __restrict__ mixed, const _Float16* __restrict__ KP,
    const _Float16* __restrict__ VP, const unsigned char* __restrict__ mask,
    _Float16* __restrict__ ctx) {
  const int qt = (int)gridDim.x - 1 - (int)blockIdx.x;  // big blocks first
  const int h = blockIdx.y, b = blockIdx.z;
  const int z = b * NHEAD + h;
  const int qb = qt * 64;
  const int tid = threadIdx.x;
  const int wave = tid >> 6, lane = tid & 63;
  const int ln = lane & 15, quad = lane >> 4;

  __shared__ _Float16 St[4][16 * 40];  // 5120 B total; per-wave P [m=16][k=32]

  const size_t RS = (size_t)BATCH * NHEAD * 384;
  const _Float16* base = mixed + (size_t)z * 384;
  const unsigned char* mbase = mask + (size_t)b * S_LEN * S_LEN;
  const float scale = 0.08838834764831845f;  // 1/sqrt(128)

  // ---- Q fragments -> registers (scaled). Wave owns rows qb+16w..+15 ----
  h8 qfrag[4];
  {
    const size_t row = (size_t)(qb + 16 * wave + ln);
#pragma unroll
    for (int kq = 0; kq < 4; kq++) {
      h8 v = *(const h8*)(base + row * RS + 32 * kq + 8 * quad);
#pragma unroll
      for (int j = 0; j < 8; j++) v[j] = (_Float16)((float)v[j] * scale);
      qfrag[kq] = v;
    }
  }

  f32x4 o[8];
#pragma unroll
  for (int nt = 0; nt < 8; nt++) o[nt] = (f32x4){0.f, 0.f, 0.f, 0.f};
  float lpart[4] = {0.f, 0.f, 0.f, 0.f};

  const int ntiles = 2 * qt + 2;  // K-tiles of 32

  for (int kt = 0; kt < ntiles; kt++) {
    const int kb = kt * 32;
    const size_t tb = ((size_t)z * 64 + kt) * 8 * 512 + lane * 8;

    // mask bytes (8 per lane)
    unsigned char mreg[4][2];
#pragma unroll
    for (int r = 0; r < 4; r++)
#pragma unroll
      for (int jn = 0; jn < 2; jn++)
        mreg[r][jn] = mbase[(size_t)(qb + 16 * wave + 4 * quad + r) * S_LEN +
                            kb + 16 * jn + ln];

    // ---- QK^T: K frags direct from packed global ----
    f32x4 s[2];
    s[0] = (f32x4){0.f, 0.f, 0.f, 0.f};
    s[1] = (f32x4){0.f, 0.f, 0.f, 0.f};
#pragma unroll
    for (int kq = 0; kq < 4; kq++) {
#pragma unroll
      for (int jn = 0; jn < 2; jn++) {
        h8 bk = *(const h8*)&KP[tb + (size_t)(jn * 4 + kq) * 512];
        s[jn] = __builtin_amdgcn_mfma_f32_16x16x32_f16(qfrag[kq], bk, s[jn], 0,
                                                       0, 0);
      }
    }

    // ---- no-max softmax -> wave-private St ----
#pragma unroll
    for (int jn = 0; jn < 2; jn++)
#pragma unroll
      for (int r = 0; r < 4; r++) {
        const int grow = qb + 16 * wave + 4 * quad + r;
        const int gcol = kb + 16 * jn + ln;
        const float sv = ((gcol > grow) || mreg[r][jn]) ? -10000.0f : s[jn][r];
        const float p = __expf(sv);
        lpart[r] += p;
        St[wave][(4 * quad + r) * 40 + 16 * jn + ln] = (_Float16)p;
      }
    __threadfence_block();

    // ---- PV: V frags direct from packed global ----
    {
      h8 ap = *(const h8*)&St[wave][ln * 40 + 8 * quad];
#pragma unroll
      for (int nt = 0; nt < 8; nt++) {
        h8 bv = *(const h8*)&VP[tb + (size_t)nt * 512];
        o[nt] = __builtin_amdgcn_mfma_f32_16x16x32_f16(ap, bv, o[nt], 0, 0, 0);
      }
    }
  }

  // ---- epilogue: single l reduction, normalize, write fp16 ctx ----
#pragma unroll
  for (int r = 0; r < 4; r++) {
    float l = lpart[r];
#pragma unroll
    for (int off = 8; off >= 1; off >>= 1) l += __shfl_xor(l, off, 16);
    const float inv_l = 1.0f / l;
    const size_t row_g = (size_t)(qb + 16 * wave + 4 * quad + r);
    _Float16* dst = ctx + (row_g * BATCH + b) * HID + h * DHEAD;
#pragma unroll
    for (int nt = 0; nt < 8; nt++)
      dst[16 * nt + ln] = (_Float16)(o[nt][r] * inv_l);
  }
}

__global__ void copy_bias(const float* __restrict__ src,
                          float* __restrict__ dst) {
  int i = blockIdx.x * blockDim.x + threadIdx.x;
  if (i < HID) dst[i] = src[i];
}

extern "C" void kernel_launch(void* const* d_in, const int* in_sizes, int n_in,
                              void* d_out, int out_size, void* d_ws,
                              size_t ws_size, hipStream_t stream) {
  (void)in_sizes;
  (void)n_in;
  const float* hs = (const float*)d_in[0];
  const unsigned char* mask = (const unsigned char*)d_in[1];
  const float* qkv_w = (const float*)d_in[2];
  const float* qkv_b = (const float*)d_in[3];
  const float* proj_w = (const float*)d_in[4];
  const float* proj_b = (const float*)d_in[5];
  float* out = (float*)d_out;

  const size_t M = (size_t)S_LEN * BATCH;
  const size_t mixed_e = M * 3 * HID;            // 25.17M halves
  const size_t qkvwt_e = (size_t)3 * HID * HID;  // 12.58M (>= VP 8.39M)
  const size_t hsh_e = M * HID;                  // 8.39M (== KP 8.39M)
  const size_t projwt_e = (size_t)HID * HID;     // 4.19M
  const size_t ctx_e = M * HID;                  // 8.39M
  const size_t need =
      (mixed_e + qkvwt_e + hsh_e + projwt_e + ctx_e) * sizeof(_Float16);
  if (ws_size < need) return;  // 117.5 MB, proven available

  _Float16* mixed = (_Float16*)d_ws;
  _Float16* qkv_wt = mixed + mixed_e;   // later aliased as VP (dead after QKV)
  _Float16* hs_h = qkv_wt + qkvwt_e;    // later aliased as KP (dead after QKV)
  _Float16* proj_wt = hs_h + hsh_e;
  _Float16* ctx = proj_wt + projwt_e;
  _Float16* KP = hs_h;
  _Float16* VP = qkv_wt;

  cvt_fp16<<<(int)(hsh_e / 4 / 256), 256, 0, stream>>>(hs, hs_h,
                                                       (int)(hsh_e / 4));
  transpose_cvt<<<dim3(3 * HID / 64, HID / 64), 256, 0, stream>>>(
      qkv_w, qkv_wt, HID, 3 * HID);
  transpose_cvt<<<dim3(HID / 64, HID / 64), 256, 0, stream>>>(
      proj_w, proj_wt, HID, HID);

  gemm_mfma<true, true><<<dim3(3 * HID / 128, M / 128), 256, 0, stream>>>(
      hs_h, qkv_wt, qkv_b, mixed, (int)M, 3 * HID, HID);

  // repack K/V into MFMA-fragment order (overwrites hs_h/qkv_wt, now dead)
  pack_kv<<<dim3(S_LEN / 32, BATCH * NHEAD), 256, 0, stream>>>(mixed, KP, VP);

  flash_attn_v6<<<dim3(S_LEN / 64, NHEAD, BATCH), 256, 0, stream>>>(
      mixed, KP, VP, mask, ctx);

  gemm_mfma<false, false><<<dim3(HID / 128, M / 128), 256, 0, stream>>>(
      ctx, proj_wt, nullptr, out, (int)M, HID, HID);

  copy_bias<<<(HID + 255) / 256, 256, 0, stream>>>(proj_b, out + M * HID);
}

// Round 9
// 465.670 us; speedup vs baseline: 1.1074x; 1.1074x over previous
//
#include <hip/hip_runtime.h>
#include <cstdint>
#include <math.h>

#define S_LEN 2048
#define BATCH 2
#define HID   2048
#define NHEAD 16
#define DHEAD 128

typedef _Float16 h8 __attribute__((ext_vector_type(8)));
typedef _Float16 h4 __attribute__((ext_vector_type(4)));
typedef float f32x4 __attribute__((ext_vector_type(4)));

// async global->LDS, 16B per lane; LDS dest = wave-uniform base + lane*16
__device__ __forceinline__ void gload16(const void* g, void* l) {
  __builtin_amdgcn_global_load_lds(
      (const __attribute__((address_space(1))) unsigned int*)g,
      (__attribute__((address_space(3))) unsigned int*)l, 16, 0, 0);
}

// ---------------------------------------------------------------------------
// fp16 MFMA GEMM (unchanged since R4): C[M,N] = A[M,K] @ Bt[N,K]^T (+bias).
// ~690 TF measured at K=2048 (m97-structure plateau).
// ---------------------------------------------------------------------------
template <bool HAS_BIAS, bool OUT_HALF>
__global__ __launch_bounds__(256) void gemm_mfma(
    const _Float16* __restrict__ A, const _Float16* __restrict__ Bt,
    const float* __restrict__ bias, void* __restrict__ Cout, int M, int N,
    int K) {
  __shared__ _Float16 As[128 * 32];
  __shared__ _Float16 Bs[128 * 32];
  const int tid = threadIdx.x;
  const int wave = tid >> 6, lane = tid & 63;
  const int ln = lane & 15, quad = lane >> 4;
  const int wm = wave & 1, wn = wave >> 1;
  const int bm = blockIdx.y * 128, bn = blockIdx.x * 128;

  const int sr = lane >> 2;
  const int sk = (lane & 3) * 8;
  const _Float16* ga0 = A + (size_t)(bm + 32 * wave + sr) * K + sk;
  const _Float16* ga1 = A + (size_t)(bm + 32 * wave + 16 + sr) * K + sk;
  const _Float16* gb0 = Bt + (size_t)(bn + 32 * wave + sr) * K + sk;
  const _Float16* gb1 = Bt + (size_t)(bn + 32 * wave + 16 + sr) * K + sk;
  _Float16* la0 = As + 1024 * wave;
  _Float16* la1 = As + 1024 * wave + 512;
  _Float16* lb0 = Bs + 1024 * wave;
  _Float16* lb1 = Bs + 1024 * wave + 512;

  f32x4 acc[4][4];
#pragma unroll
  for (int i = 0; i < 4; i++)
#pragma unroll
    for (int j = 0; j < 4; j++) acc[i][j] = (f32x4){0.f, 0.f, 0.f, 0.f};

  for (int kt = 0; kt < K; kt += 32) {
    __syncthreads();
    gload16(ga0 + kt, la0);
    gload16(ga1 + kt, la1);
    gload16(gb0 + kt, lb0);
    gload16(gb1 + kt, lb1);
    __syncthreads();

    h8 af[4], bf[4];
#pragma unroll
    for (int mt = 0; mt < 4; mt++)
      af[mt] = *(const h8*)&As[(wm * 64 + mt * 16 + ln) * 32 + quad * 8];
#pragma unroll
    for (int nt = 0; nt < 4; nt++)
      bf[nt] = *(const h8*)&Bs[(wn * 64 + nt * 16 + ln) * 32 + quad * 8];
#pragma unroll
    for (int mt = 0; mt < 4; mt++)
#pragma unroll
      for (int nt = 0; nt < 4; nt++)
        acc[mt][nt] = __builtin_amdgcn_mfma_f32_16x16x32_f16(
            af[mt], bf[nt], acc[mt][nt], 0, 0, 0);
  }

#pragma unroll
  for (int mt = 0; mt < 4; mt++) {
#pragma unroll
    for (int r = 0; r < 4; r++) {
      const size_t row = (size_t)(bm + wm * 64 + mt * 16 + quad * 4 + r);
#pragma unroll
      for (int nt = 0; nt < 4; nt++) {
        const int col = bn + wn * 64 + nt * 16 + ln;
        float v = acc[mt][nt][r];
        if (HAS_BIAS) v += bias[col];
        if (OUT_HALF)
          ((_Float16*)Cout)[row * N + col] = (_Float16)v;
        else
          ((float*)Cout)[row * N + col] = v;
      }
    }
  }
}

__global__ __launch_bounds__(256) void transpose_cvt(
    const float* __restrict__ in, _Float16* __restrict__ out, int K, int N) {
  __shared__ float t[64][65];
  const int bn = blockIdx.x * 64, bk = blockIdx.y * 64;
  const int l = threadIdx.x & 63, g = threadIdx.x >> 6;
#pragma unroll
  for (int i = 0; i < 16; i++) {
    int r = g + 4 * i;
    t[r][l] = in[(size_t)(bk + r) * N + bn + l];
  }
  __syncthreads();
#pragma unroll
  for (int i = 0; i < 16; i++) {
    int r = g + 4 * i;
    out[(size_t)(bn + r) * K + bk + l] = (_Float16)t[l][r];
  }
}

__global__ __launch_bounds__(256) void cvt_fp16(const float* __restrict__ in,
                                                _Float16* __restrict__ out,
                                                int n4) {
  int i = blockIdx.x * blockDim.x + threadIdx.x;
  if (i < n4) {
    float4 v = ((const float4*)in)[i];
    h4 o = {(_Float16)v.x, (_Float16)v.y, (_Float16)v.z, (_Float16)v.w};
    *(h4*)&out[4 * (size_t)i] = o;
  }
}

// ---------------------------------------------------------------------------
// pack_kv (unchanged since R8): K/V of each (z, kt) 32-row tile re-laid into
// MFMA-fragment lane order. Chunk c of a tile is 1 KB contiguous:
//   KP[tile_base + c*512 + lane*8 + j], c = jn*4+kq (K) / c = nt (V).
// This is exactly the wave-uniform-base + lane*16B shape global_load_lds
// needs, so flash staging is a straight async copy.
// ---------------------------------------------------------------------------
__global__ __launch_bounds__(256) void pack_kv(
    const _Float16* __restrict__ mixed, _Float16* __restrict__ KP,
    _Float16* __restrict__ VP) {
  __shared__ _Float16 Tv[128 * 40];
  const int kt = blockIdx.x;
  const int z = blockIdx.y;  // b*NH + h
  const int kb = kt * 32;
  const int tid = threadIdx.x;
  const size_t RS = (size_t)BATCH * NHEAD * 384;
  const _Float16* base = mixed + (size_t)z * 384;

  // Phase A: stage V tile transposed into Tv
  {
    const int r = tid >> 3, d0 = (tid & 7) * 16;
    const _Float16* src = base + (size_t)(kb + r) * RS + 256 + d0;
    h8 v0 = *(const h8*)src;
    h8 v1 = *(const h8*)(src + 8);
#pragma unroll
    for (int e = 0; e < 8; e++) Tv[(d0 + e) * 40 + r] = v0[e];
#pragma unroll
    for (int e = 0; e < 8; e++) Tv[(d0 + 8 + e) * 40 + r] = v1[e];
  }
  __syncthreads();

  const size_t tb = ((size_t)z * 64 + kt) * 8 * 512;
#pragma unroll
  for (int c = 0; c < 2; c++) {
    const int idx = tid + 256 * c;  // 0..511
    const int i = idx >> 6, l = idx & 63;
    const int ln = l & 15, quad = l >> 4;
    {
      const int jn = i >> 2, kq = i & 3;
      h8 v = *(const h8*)(base + (size_t)(kb + 16 * jn + ln) * RS + 128 +
                          32 * kq + 8 * quad);
      *(h8*)&KP[tb + (size_t)i * 512 + l * 8] = v;
    }
    {
      h8 v = *(const h8*)&Tv[(16 * i + ln) * 40 + 8 * quad];
      *(h8*)&VP[tb + (size_t)i * 512 + l * 8] = v;
    }
  }
}

// ---------------------------------------------------------------------------
// fp16-MFMA flash attention v7: LDS double-buffer + ONE barrier/tile +
// async global_load_lds from frag-ordered KP/VP.
// R9 rationale: v6 (zero-staging) was Infinity-Cache-BW-bound — 4 waves each
// privately re-reading the 16 KB tile = 2.16 GB logical at ~14 TB/s ~= the
// whole 168 us. Staging through LDS cuts traffic 4x (540 MB); double-buffer
// means the tile-(kt+1) loads issued right after the barrier have a full
// tile of compute to land, so the vmcnt(0)+s_barrier drain is ~free.
// Grid (S/64, NH, B), 256 thr; wave owns 16 q-rows. LDS 37,888 B -> 4
// blocks/CU (16 waves). Reg-Q, no-max softmax, wave-private St (unchanged).
// ---------------------------------------------------------------------------
__global__ __launch_bounds__(256) void flash_attn_v7(
    const _Float16* __restrict__ mixed, const _Float16* __restrict__ KP,
    const _Float16* __restrict__ VP, const unsigned char* __restrict__ mask,
    _Float16* __restrict__ ctx) {
  const int qt = (int)gridDim.x - 1 - (int)blockIdx.x;  // big blocks first
  const int h = blockIdx.y, b = blockIdx.z;
  const int z = b * NHEAD + h;
  const int qb = qt * 64;
  const int tid = threadIdx.x;
  const int wave = tid >> 6, lane = tid & 63;
  const int ln = lane & 15, quad = lane >> 4;

  __shared__ _Float16 Kbuf[2][8 * 512];  // 2 x 8 KB, frag-chunk layout
  __shared__ _Float16 Vbuf[2][8 * 512];  // 2 x 8 KB
  __shared__ _Float16 St[4][16 * 40];    // 5 KB, per-wave P [m=16][k=32]

  const size_t RS = (size_t)BATCH * NHEAD * 384;
  const _Float16* base = mixed + (size_t)z * 384;
  const unsigned char* mbase = mask + (size_t)b * S_LEN * S_LEN;
  const float scale = 0.08838834764831845f;  // 1/sqrt(128)

  // ---- Q fragments -> registers (scaled). Wave owns rows qb+16w..+15 ----
  h8 qfrag[4];
  {
    const size_t row = (size_t)(qb + 16 * wave + ln);
#pragma unroll
    for (int kq = 0; kq < 4; kq++) {
      h8 v = *(const h8*)(base + row * RS + 32 * kq + 8 * quad);
#pragma unroll
      for (int j = 0; j < 8; j++) v[j] = (_Float16)((float)v[j] * scale);
      qfrag[kq] = v;
    }
  }

  f32x4 o[8];
#pragma unroll
  for (int nt = 0; nt < 8; nt++) o[nt] = (f32x4){0.f, 0.f, 0.f, 0.f};
  float lpart[4] = {0.f, 0.f, 0.f, 0.f};

  const int ntiles = 2 * qt + 2;  // K-tiles of 32

  // stage tile kt into buffer buf: wave stages K chunks {2w,2w+1} and
  // V chunks {2w,2w+1}; each chunk = 1 KB contiguous (64 lanes x 16 B).
  const size_t zt = (size_t)z * 64;
#define STAGE(kt_, buf_)                                                   \
  {                                                                        \
    const size_t tbk = (zt + (kt_)) * (8 * 512) + lane * 8;                \
    _Pragma("unroll") for (int c = 0; c < 2; c++) {                        \
      const int ch = 2 * wave + c;                                         \
      gload16(KP + tbk + ch * 512, &Kbuf[buf_][ch * 512]);                 \
      gload16(VP + tbk + ch * 512, &Vbuf[buf_][ch * 512]);                 \
    }                                                                      \
  }

  STAGE(0, 0)  // prologue

  for (int kt = 0; kt < ntiles; kt++) {
    const int kb = kt * 32;
    const int cur = kt & 1;
    __syncthreads();  // drains this tile's async loads; frees other buffer

    if (kt + 1 < ntiles) STAGE(kt + 1, cur ^ 1)  // lands during this compute

    // mask bytes (8 per lane)
    unsigned char mreg[4][2];
#pragma unroll
    for (int r = 0; r < 4; r++)
#pragma unroll
      for (int jn = 0; jn < 2; jn++)
        mreg[r][jn] = mbase[(size_t)(qb + 16 * wave + 4 * quad + r) * S_LEN +
                            kb + 16 * jn + ln];

    // ---- QK^T: K frags from LDS chunk layout ----
    f32x4 s[2];
    s[0] = (f32x4){0.f, 0.f, 0.f, 0.f};
    s[1] = (f32x4){0.f, 0.f, 0.f, 0.f};
#pragma unroll
    for (int kq = 0; kq < 4; kq++) {
#pragma unroll
      for (int jn = 0; jn < 2; jn++) {
        h8 bk = *(const h8*)&Kbuf[cur][(jn * 4 + kq) * 512 + lane * 8];
        s[jn] = __builtin_amdgcn_mfma_f32_16x16x32_f16(qfrag[kq], bk, s[jn], 0,
                                                       0, 0);
      }
    }

    // ---- no-max softmax -> wave-private St ----
#pragma unroll
    for (int jn = 0; jn < 2; jn++)
#pragma unroll
      for (int r = 0; r < 4; r++) {
        const int grow = qb + 16 * wave + 4 * quad + r;
        const int gcol = kb + 16 * jn + ln;
        const float sv = ((gcol > grow) || mreg[r][jn]) ? -10000.0f : s[jn][r];
        const float p = __expf(sv);
        lpart[r] += p;
        St[wave][(4 * quad + r) * 40 + 16 * jn + ln] = (_Float16)p;
      }
    __threadfence_block();

    // ---- PV: V frags from LDS chunk layout ----
    {
      h8 ap = *(const h8*)&St[wave][ln * 40 + 8 * quad];
#pragma unroll
      for (int nt = 0; nt < 8; nt++) {
        h8 bv = *(const h8*)&Vbuf[cur][nt * 512 + lane * 8];
        o[nt] = __builtin_amdgcn_mfma_f32_16x16x32_f16(ap, bv, o[nt], 0, 0, 0);
      }
    }
  }
#undef STAGE

  // ---- epilogue: single l reduction, normalize, write fp16 ctx ----
#pragma unroll
  for (int r = 0; r < 4; r++) {
    float l = lpart[r];
#pragma unroll
    for (int off = 8; off >= 1; off >>= 1) l += __shfl_xor(l, off, 16);
    const float inv_l = 1.0f / l;
    const size_t row_g = (size_t)(qb + 16 * wave + 4 * quad + r);
    _Float16* dst = ctx + (row_g * BATCH + b) * HID + h * DHEAD;
#pragma unroll
    for (int nt = 0; nt < 8; nt++)
      dst[16 * nt + ln] = (_Float16)(o[nt][r] * inv_l);
  }
}

__global__ void copy_bias(const float* __restrict__ src,
                          float* __restrict__ dst) {
  int i = blockIdx.x * blockDim.x + threadIdx.x;
  if (i < HID) dst[i] = src[i];
}

extern "C" void kernel_launch(void* const* d_in, const int* in_sizes, int n_in,
                              void* d_out, int out_size, void* d_ws,
                              size_t ws_size, hipStream_t stream) {
  (void)in_sizes;
  (void)n_in;
  const float* hs = (const float*)d_in[0];
  const unsigned char* mask = (const unsigned char*)d_in[1];
  const float* qkv_w = (const float*)d_in[2];
  const float* qkv_b = (const float*)d_in[3];
  const float* proj_w = (const float*)d_in[4];
  const float* proj_b = (const float*)d_in[5];
  float* out = (float*)d_out;

  const size_t M = (size_t)S_LEN * BATCH;
  const size_t mixed_e = M * 3 * HID;            // 25.17M halves
  const size_t qkvwt_e = (size_t)3 * HID * HID;  // 12.58M (>= VP 8.39M)
  const size_t hsh_e = M * HID;                  // 8.39M (== KP 8.39M)
  const size_t projwt_e = (size_t)HID * HID;     // 4.19M
  const size_t ctx_e = M * HID;                  // 8.39M
  const size_t need =
      (mixed_e + qkvwt_e + hsh_e + projwt_e + ctx_e) * sizeof(_Float16);
  if (ws_size < need) return;  // 117.5 MB, proven available

  _Float16* mixed = (_Float16*)d_ws;
  _Float16* qkv_wt = mixed + mixed_e;   // aliased as VP after QKV GEMM
  _Float16* hs_h = qkv_wt + qkvwt_e;    // aliased as KP after QKV GEMM
  _Float16* proj_wt = hs_h + hsh_e;
  _Float16* ctx = proj_wt + projwt_e;
  _Float16* KP = hs_h;
  _Float16* VP = qkv_wt;

  cvt_fp16<<<(int)(hsh_e / 4 / 256), 256, 0, stream>>>(hs, hs_h,
                                                       (int)(hsh_e / 4));
  transpose_cvt<<<dim3(3 * HID / 64, HID / 64), 256, 0, stream>>>(
      qkv_w, qkv_wt, HID, 3 * HID);
  transpose_cvt<<<dim3(HID / 64, HID / 64), 256, 0, stream>>>(
      proj_w, proj_wt, HID, HID);

  gemm_mfma<true, true><<<dim3(3 * HID / 128, M / 128), 256, 0, stream>>>(
      hs_h, qkv_wt, qkv_b, mixed, (int)M, 3 * HID, HID);

  pack_kv<<<dim3(S_LEN / 32, BATCH * NHEAD), 256, 0, stream>>>(mixed, KP, VP);

  flash_attn_v7<<<dim3(S_LEN / 64, NHEAD, BATCH), 256, 0, stream>>>(
      mixed, KP, VP, mask, ctx);

  gemm_mfma<false, false><<<dim3(HID / 128, M / 128), 256, 0, stream>>>(
      ctx, proj_wt, nullptr, out, (int)M, HID, HID);

  copy_bias<<<(HID + 255) / 256, 256, 0, stream>>>(proj_b, out + M * HID);
}